// Round 4
// baseline (1189.365 us; speedup 1.0000x reference)
//
#include <hip/hip_runtime.h>

// WindowAttentionBlock: B=4096 windows, N=49 tokens, D=384, H=12 heads, hd=32.
// v4: software-pipelined head-pair loop.
//  - QKV projection of pair p+1 (MFMA + global wb loads, no LDS) placed in the
//    same branchless region as softmax of pair p (pure VALU) -> MFMA and VALU
//    pipes co-fill within a wave (counters showed each pipe ~20% busy,
//    phase-serialized).
//  - deferred softmax normalization: P packed un-normalized (exp <= 1), 1/sum
//    folded into the O store (aO*inv) -> pack no longer waits on sum tree.
//  - structure: prologue QKV_0 | 5x body {scores_p; QKV_{p+1} || softmax_p;
//    PV_p; Ostore; BAR; storeQKV_{p+1}; BAR} | epilogue attn_5 | out-proj.
//  - all v3.1 fragment index math kept verbatim (verified passing).

#define NWIN   4096
#define NTOK   49
#define DMODEL 384
#define NH     12
#define HD     32
#define XPITCH 392   // x/O row pitch in shorts (384+8)
#define QP     40    // Q/K row pitch (32+8)
#define VP     72    // Vt row pitch (64+8)
#define SCALE  2.9802322387695312e-08f   // (32)^-5, faithful to reference
#define NEGBIG -30000.0f

#define S_BASE 19208          // scratch start (shorts)
#define S_STR  6224           // per-head-slot scratch size (shorts)
#define LDS_TOT 31656         // 63312 B

typedef __attribute__((ext_vector_type(8)))  short short8;
typedef __attribute__((ext_vector_type(4)))  short short4v;
typedef __attribute__((ext_vector_type(4)))  float float4v;
typedef __attribute__((ext_vector_type(16))) float float16v;

__device__ __align__(16) unsigned short g_wT[4 * DMODEL * DMODEL];
__device__ int g_dt;   // 0 = bf16 tensors, 1 = fp32 tensors

__device__ __forceinline__ float b2f(unsigned short h) {
  union { unsigned u; float f; } t; t.u = ((unsigned)h) << 16; return t.f;
}
__device__ __forceinline__ unsigned short f2b(float f) {
  union { float f; unsigned u; } t; t.f = f;
  return (unsigned short)((t.u + 0x7fffu + ((t.u >> 16) & 1u)) >> 16);
}
__device__ __forceinline__ unsigned cvt_pk_bf16(float lo, float hi) {
  unsigned r;
  asm("v_cvt_pk_bf16_f32 %0, %1, %2" : "=v"(r) : "v"(lo), "v"(hi));
  return r;
}

__global__ void detect_dtype(const unsigned short* __restrict__ x) {
  __shared__ int cnt;
  if (threadIdx.x == 0) cnt = 0;
  __syncthreads();
  int local = 0;
  for (int i = threadIdx.x; i < 2048; i += 256) {
    unsigned short h = x[2 * i];
    int e = (h >> 7) & 0xFF;
    if (e >= 0x6A && e <= 0x90) local++;
  }
  atomicAdd(&cnt, local);
  __syncthreads();
  if (threadIdx.x == 0) g_dt = (cnt < 1024) ? 1 : 0;
}

// Weight prep (unchanged from v3.1).
// QKV region [0, 442368): 32x32x16 B-fragment tiles, 512 shorts each.
//   tile t = (h*24 + ks)*3 + mat; element l*8+j = W_mat[ks*16+(l>>5)*8+j][h*32+(l&31)]
// Wp region [442368, 589824): 16x16x32 tiles.
//   tile t' = (wv*12 + ks)*6 + nt; element l*8+j = Wp[ks*32+(l>>4)*8+j][wv*96+nt*16+(l&15)]
__global__ void prep_weights(const void* __restrict__ Wq,
                             const void* __restrict__ Wk,
                             const void* __restrict__ Wv,
                             const void* __restrict__ Wp) {
  int o = blockIdx.x * 256 + threadIdx.x;
  int e = o & 511;
  int t = o >> 9;
  int l = e >> 3, j = e & 7;
  int k, col;
  const void* W;
  if (t < 864) {
    int h = t / 72, r = t - h * 72;
    int ks = r / 3, mat = r - ks * 3;
    W = (mat == 0) ? Wq : (mat == 1) ? Wk : Wv;
    k = ks * 16 + (l >> 5) * 8 + j;
    col = h * 32 + (l & 31);
  } else {
    int tp = t - 864;
    int wv = tp / 72, r = tp - wv * 72;
    int ks = r / 6, nt = r - ks * 6;
    W = Wp;
    k = ks * 32 + (l >> 4) * 8 + j;
    col = wv * 96 + nt * 16 + (l & 15);
  }
  unsigned short v;
  if (g_dt) v = f2b(((const float*)W)[k * DMODEL + col]);
  else      v = ((const unsigned short*)W)[k * DMODEL + col];
  g_wT[o] = v;
}

// Barrier with LDS-only drain: global register prefetches stay in flight.
#define BAR() do {                                          \
    asm volatile("s_waitcnt lgkmcnt(0)" ::: "memory");      \
    __builtin_amdgcn_s_barrier();                           \
    asm volatile("" ::: "memory");                          \
  } while (0)

#define MFMA32(A, B, C) __builtin_amdgcn_mfma_f32_32x32x16_bf16((A), (B), (C), 0, 0, 0)
#define MFMA16(A, B, C) __builtin_amdgcn_mfma_f32_16x16x32_bf16((A), (B), (C), 0, 0, 0)

__global__ __launch_bounds__(256, 2)
void win_attn(const void* __restrict__ xg_,
              const void* __restrict__ maskg_,
              const void* __restrict__ bqg_,
              const void* __restrict__ bkg_,
              const void* __restrict__ bvg_,
              const void* __restrict__ bpg_,
              void* __restrict__ outg_)
{
  __shared__ __align__(16) short lds[LDS_TOT];
  const int dt   = g_dt;
  const int win  = blockIdx.x;
  const int tid  = threadIdx.x;
  const int wv   = tid >> 6;
  const int lane = tid & 63;
  const int cl   = lane & 31;      // 32-wide col index (attn core)
  const int hi   = lane >> 5;      // half-wave
  const int c    = lane & 15;      // 16-wide col index (out-proj)
  const int qd   = lane >> 4;
  const int b    = wv & 1;         // q-band (rows b*32 .. b*32+31)
  const int h2   = wv >> 1;        // head-of-pair slot

  const unsigned short* const wl = g_wT + lane * 8;
  const unsigned short* const wp = g_wT + 442368 + wv * 36864 + lane * 8;

  // ---- earliest weight prefetch: head h2, ks 0..3 (12 tiles) ----
  short8 wb[12];
  {
    const unsigned short* w0 = wl + (h2 * 72) * 512;
    #pragma unroll
    for (int t = 0; t < 12; ++t) wb[t] = *(const short8*)(w0 + t * 512);
  }

  // ---- zero-init scratch (Vt pad rows must be 0) ----
  {
    unsigned* z = (unsigned*)&lds[S_BASE];
    for (int i = tid; i < 6224; i += 256) z[i] = 0u;
  }

  // ---- stage x window into LDS as bf16 ----
  if (dt == 0) {
    const uint4* src = (const uint4*)((const unsigned short*)xg_ + (size_t)win * (NTOK * DMODEL));
    for (int i = tid; i < (NTOK * DMODEL) / 8; i += 256) {
      int row = i / 48, col = i - row * 48;
      *(uint4*)&lds[row * XPITCH + col * 8] = src[i];
    }
  } else {
    const float4* src = (const float4*)((const float*)xg_ + (size_t)win * (NTOK * DMODEL));
    for (int i = tid; i < (NTOK * DMODEL) / 4; i += 256) {
      int row = i / 96, colq = i - row * 96;
      float4 f = src[i];
      short4v p;
      p[0] = (short)f2b(f.x); p[1] = (short)f2b(f.y);
      p[2] = (short)f2b(f.z); p[3] = (short)f2b(f.w);
      *(short4v*)&lds[row * XPITCH + colq * 4] = p;
    }
  }

  short* const sQh = lds + S_BASE + h2 * S_STR;
  short* const sKh = sQh + 1960;
  short* const sVt = sQh + 3920;
  short* const sO  = lds;          // x region becomes O after xa hoist

  // ---- packed mask additions: lane's 32 keys for its q-row (bf16 pairs) ----
  unsigned maddpk[16];
  {
    int qrow = b * 32 + cl; if (qrow > NTOK - 1) qrow = NTOK - 1;
    const size_t mb = (size_t)win * (NTOK * NTOK) + (size_t)qrow * NTOK;
    #pragma unroll
    for (int kt = 0; kt < 2; ++kt)
      #pragma unroll
      for (int i = 0; i < 8; ++i) {
        int k0 = kt * 32 + ((2 * i) & 3) + 8 * ((2 * i) >> 2) + 4 * hi;  // even
        float m0 = (k0     < NTOK)
          ? (dt ? ((const float*)maskg_)[mb + k0]     : b2f(((const unsigned short*)maskg_)[mb + k0]))
          : NEGBIG;
        float m1 = (k0 + 1 < NTOK)
          ? (dt ? ((const float*)maskg_)[mb + k0 + 1] : b2f(((const unsigned short*)maskg_)[mb + k0 + 1]))
          : NEGBIG;
        maddpk[kt * 8 + i] = cvt_pk_bf16(m0, m1);
      }
  }

  BAR();   // x staged + scratch zeroed

  // ---- hoist x A-fragments for this wave's 32-row band (48 VGPRs) ----
  short8 xa[24];
  {
    const int xrow = b * 32 + cl;
    const int xr   = (xrow < NTOK) ? xrow : 0;
    const short8 z8 = {0, 0, 0, 0, 0, 0, 0, 0};
    #pragma unroll
    for (int ks = 0; ks < 24; ++ks) {
      short8 t = *(const short8*)&lds[xr * XPITCH + ks * 16 + hi * 8];
      xa[ks] = (xrow < NTOK) ? t : z8;
    }
  }

  // ---- QKV compute: 24 K-steps of 16, rolling prefetch distance 4 ----
  auto qkv_pass = [&](const unsigned short* whn, const unsigned short* pfNext,
                      float16v& q, float16v& k, float16v& v) {
    #pragma unroll
    for (int i = 0; i < 16; ++i) { q[i] = 0.f; k[i] = 0.f; v[i] = 0.f; }
    #pragma unroll
    for (int ks = 0; ks < 24; ++ks) {
      const int s = (ks & 3) * 3;
      const short8 a = xa[ks];
      q = MFMA32(a, wb[s + 0], q);
      k = MFMA32(a, wb[s + 1], k);
      v = MFMA32(a, wb[s + 2], v);
      const unsigned short* pf = (ks < 20) ? (whn + ((ks + 4) * 3) * 512)
                                           : (pfNext + ((ks - 20) * 3) * 512);
      wb[s + 0] = *(const short8*)(pf + 0 * 512);
      wb[s + 1] = *(const short8*)(pf + 1 * 512);
      wb[s + 2] = *(const short8*)(pf + 2 * 512);
    }
  };

  // ---- QKV store: Q,K row-major [tok][hd]; V transposed [hd][tok] ----
  auto qkv_store = [&](const float16v& q, const float16v& k, const float16v& v,
                       float bQ, float bK, float bV) {
    #pragma unroll
    for (int i = 0; i < 16; ++i) {
      const int tok = (i & 3) + 8 * (i >> 2) + 4 * hi + b * 32;
      if (tok < NTOK) {
        sQh[tok * QP + cl] = (short)f2b(q[i] + bQ);
        sKh[tok * QP + cl] = (short)f2b(k[i] + bK);
      }
    }
    #pragma unroll
    for (int i = 0; i < 8; ++i) {
      const int tok = ((2 * i) & 3) + 8 * ((2 * i) >> 2) + 4 * hi + b * 32; // even
      if (tok < NTOK) {
        float v0 = v[2 * i] + bV;
        float v1 = (tok + 1 < NTOK) ? (v[2 * i + 1] + bV) : 0.f;
        *(unsigned*)&sVt[cl * VP + tok] = cvt_pk_bf16(v0, v1);
      }
    }
  };

  // ---- scores (into S0/S1): S^T[key][q] = mfma(A=K, B=Q) ----
  auto scores = [&](float16v& S0, float16v& S1) {
    #pragma unroll
    for (int i = 0; i < 16; ++i) { S0[i] = 0.f; S1[i] = 0.f; }
    int qr  = b * 32 + cl; if (qr > NTOK - 1) qr = NTOK - 1;
    const int kr0 = cl;
    int kr1 = 32 + cl; if (kr1 > NTOK - 1) kr1 = NTOK - 1;
    #pragma unroll
    for (int ks = 0; ks < 2; ++ks) {
      const short8 qf  = *(const short8*)&sQh[qr  * QP + ks * 16 + hi * 8];
      const short8 kf0 = *(const short8*)&sKh[kr0 * QP + ks * 16 + hi * 8];
      const short8 kf1 = *(const short8*)&sKh[kr1 * QP + ks * 16 + hi * 8];
      S0 = MFMA32(kf0, qf, S0);
      S1 = MFMA32(kf1, qf, S1);
    }
  };

  // ---- softmax (un-normalized pack) + PV + O store (x region) ----
  auto softmax_pv_store = [&](int h, const float16v& S0, const float16v& S1) {
    float w32[32];
    #pragma unroll
    for (int kt = 0; kt < 2; ++kt)
      #pragma unroll
      for (int i = 0; i < 8; ++i) {
        const unsigned pk = maddpk[kt * 8 + i];
        const float m0 = __uint_as_float(pk << 16);
        const float m1 = __uint_as_float(pk & 0xffff0000u);
        const float sv0 = kt ? S1[2 * i]     : S0[2 * i];
        const float sv1 = kt ? S1[2 * i + 1] : S0[2 * i + 1];
        w32[kt * 16 + 2 * i]     = fmaf(sv0, SCALE, m0);
        w32[kt * 16 + 2 * i + 1] = fmaf(sv1, SCALE, m1);
      }
    float t16[16], t8[8], t4[4];
    #pragma unroll
    for (int i = 0; i < 16; ++i) t16[i] = fmaxf(w32[2 * i], w32[2 * i + 1]);
    #pragma unroll
    for (int i = 0; i < 8; ++i)  t8[i] = fmaxf(t16[2 * i], t16[2 * i + 1]);
    #pragma unroll
    for (int i = 0; i < 4; ++i)  t4[i] = fmaxf(t8[2 * i], t8[2 * i + 1]);
    float mx = fmaxf(fmaxf(t4[0], t4[1]), fmaxf(t4[2], t4[3]));
    mx = fmaxf(mx, __shfl_xor(mx, 32));
    #pragma unroll
    for (int i = 0; i < 32; ++i) w32[i] = __expf(w32[i] - mx);
    // sum tree (independent of the pack below; inv consumed only at O store)
    #pragma unroll
    for (int i = 0; i < 16; ++i) t16[i] = w32[2 * i] + w32[2 * i + 1];
    #pragma unroll
    for (int i = 0; i < 8; ++i)  t8[i] = t16[2 * i] + t16[2 * i + 1];
    #pragma unroll
    for (int i = 0; i < 4; ++i)  t4[i] = t8[2 * i] + t8[2 * i + 1];
    float sum = (t4[0] + t4[1]) + (t4[2] + t4[3]);
    sum += __shfl_xor(sum, 32);
    const float inv = 1.0f / sum;   // sum >= 1 always

    // pack un-normalized P (exp <= 1) + partner exchange -> PV A-fragments
    unsigned pw[16];
    #pragma unroll
    for (int i = 0; i < 16; ++i)
      pw[i] = cvt_pk_bf16(w32[2 * i], w32[2 * i + 1]);
    short8 pa[4];
    #pragma unroll
    for (int ks = 0; ks < 4; ++ks) {
      const unsigned q0 = pw[ks * 4 + 0], q1 = pw[ks * 4 + 1];
      const unsigned q2 = pw[ks * 4 + 2], q3 = pw[ks * 4 + 3];
      const unsigned t0 = hi ? q0 : q2;
      const unsigned t1 = hi ? q1 : q3;
      const unsigned x0 = __shfl_xor(t0, 32);
      const unsigned x1 = __shfl_xor(t1, 32);
      union { unsigned u[4]; short8 s; } u;
      u.u[0] = hi ? x0 : q0;
      u.u[1] = hi ? x1 : q1;
      u.u[2] = hi ? q2 : x0;
      u.u[3] = hi ? q3 : x1;
      pa[ks] = u.s;
    }

    // PV: O[q][hd] = P @ Vt, K-dim = 64 keys = 4 steps of 16
    float16v aO;
    #pragma unroll
    for (int i = 0; i < 16; ++i) aO[i] = 0.f;
    #pragma unroll
    for (int ks = 0; ks < 4; ++ks) {
      const short8 bv8 = *(const short8*)&sVt[cl * VP + ks * 16 + hi * 8];
      aO = MFMA32(pa[ks], bv8, aO);
    }

    // O store with deferred normalization
    #pragma unroll
    for (int i = 0; i < 16; ++i) {
      const int tok = (i & 3) + 8 * (i >> 2) + 4 * hi + b * 32;
      if (tok < NTOK)
        sO[tok * XPITCH + h * 32 + cl] = (short)f2b(aO[i] * inv);
    }
  };

  auto load_bias = [&](const void* bg, int col) -> float {
    return dt ? ((const float*)bg)[col] : b2f(((const unsigned short*)bg)[col]);
  };

  // ================= PROLOGUE: QKV for pair 0 (head h2) =================
  float16v qA, kA, vA;
  {
    const int hn = h2;
    const float bQ = load_bias(bqg_, hn * 32 + cl);
    const float bK = load_bias(bkg_, hn * 32 + cl);
    const float bV = load_bias(bvg_, hn * 32 + cl);
    qkv_pass(wl + hn * 72 * 512, wl + (hn + 2) * 72 * 512, qA, kA, vA);
    qkv_store(qA, kA, vA, bQ, bK, bV);
  }
  BAR();   // slot(h2) visible

  // ================= BODY: p = 0..4 =================
  #pragma unroll 1
  for (int p = 0; p < 5; ++p) {
    const int h  = 2 * p + h2;
    const int hn = h + 2;
    // issue next pair's bias loads early (consumed after BAR A)
    const float bQ = load_bias(bqg_, hn * 32 + cl);
    const float bK = load_bias(bkg_, hn * 32 + cl);
    const float bV = load_bias(bvg_, hn * 32 + cl);

    float16v S0, S1;
    scores(S0, S1);

    // overlap region: QKV_{p+1} (MFMA + global loads) || softmax_p (VALU).
    // One branchless region until the guarded stores; the BB scheduler
    // interleaves the independent chains.
    const unsigned short* pfNext = (p == 4) ? wp : (wl + (hn + 2) * 72 * 512);
    qkv_pass(wl + hn * 72 * 512, pfNext, qA, kA, vA);
    softmax_pv_store(h, S0, S1);

    BAR();   // (A) all waves done reading slot h
    qkv_store(qA, kA, vA, bQ, bK, bV);
    BAR();   // (B) slot hn visible
  }

  // ================= EPILOGUE: attn for pair 5 =================
  {
    const int h = 10 + h2;
    float16v S0, S1;
    scores(S0, S1);
    softmax_pv_store(h, S0, S1);
  }
  BAR();   // O complete for out-proj

  // ---- output projection: each wave 96 cols; out = O @ Wp + bp ----
  // wb[0..11] hold Wp tiles 0..11 (prefetched during p==4's qkv_pass tail).
  float biasP[6];
  #pragma unroll
  for (int nt = 0; nt < 6; ++nt) {
    const int col = wv * 96 + nt * 16 + c;
    biasP[nt] = load_bias(bpg_, col);
  }

  const float4v z4 = {0.f, 0.f, 0.f, 0.f};
  float4v aP[4][6];
  #pragma unroll
  for (int mt = 0; mt < 4; ++mt)
    #pragma unroll
    for (int nt = 0; nt < 6; ++nt) aP[mt][nt] = z4;

  short8 af[2][4];
  #pragma unroll
  for (int mt = 0; mt < 4; ++mt) {
    int row = mt * 16 + c; if (row > NTOK - 1) row = NTOK - 1;
    af[0][mt] = *(const short8*)&sO[row * XPITCH + qd * 8];
  }

  #pragma unroll
  for (int ks = 0; ks < 12; ++ks) {
    const int cs = ks & 1;
    if (ks < 11) {
      #pragma unroll
      for (int mt = 0; mt < 4; ++mt) {
        int row = mt * 16 + c; if (row > NTOK - 1) row = NTOK - 1;
        af[cs ^ 1][mt] = *(const short8*)&sO[row * XPITCH + (ks + 1) * 32 + qd * 8];
      }
    }
    const int s = cs * 6;
    #pragma unroll
    for (int nt = 0; nt < 6; ++nt) {
      aP[0][nt] = MFMA16(af[cs][0], wb[s + nt], aP[0][nt]);
      aP[1][nt] = MFMA16(af[cs][1], wb[s + nt], aP[1][nt]);
      aP[2][nt] = MFMA16(af[cs][2], wb[s + nt], aP[2][nt]);
      aP[3][nt] = MFMA16(af[cs][3], wb[s + nt], aP[3][nt]);
      if (ks < 10) wb[s + nt] = *(const short8*)(wp + ((ks + 2) * 6 + nt) * 512);
    }
  }

  #pragma unroll
  for (int nt = 0; nt < 6; ++nt) {
    const int col = wv * 96 + nt * 16 + c;
    #pragma unroll
    for (int mt = 0; mt < 4; ++mt) {
      #pragma unroll
      for (int r = 0; r < 4; ++r) {
        const int m = mt * 16 + qd * 4 + r;
        if (m < NTOK) {
          const float v = aP[mt][nt][r] + biasP[nt];
          const size_t off = (size_t)win * (NTOK * DMODEL) + m * DMODEL + col;
          if (dt) ((float*)outg_)[off] = v;
          else    ((unsigned short*)outg_)[off] = f2b(v);
        }
      }
    }
  }
}

extern "C" void kernel_launch(void* const* d_in, const int* in_sizes, int n_in,
                              void* d_out, int out_size, void* d_ws, size_t ws_size,
                              hipStream_t stream) {
  const void* x    = d_in[0];
  const void* mask = d_in[1];
  const void* Wq   = d_in[2];
  const void* bq   = d_in[3];
  const void* Wk   = d_in[4];
  const void* bk   = d_in[5];
  const void* Wv   = d_in[6];
  const void* bv   = d_in[7];
  const void* Wp   = d_in[8];
  const void* bp   = d_in[9];

  detect_dtype<<<1, 256, 0, stream>>>((const unsigned short*)x);
  prep_weights<<<(4 * DMODEL * DMODEL) / 256, 256, 0, stream>>>(Wq, Wk, Wv, Wp);
  win_attn<<<NWIN, 256, 0, stream>>>(x, mask, bq, bk, bv, bp, d_out);
}